// Round 19
// baseline (138.215 us; speedup 1.0000x reference)
//
#include <hip/hip_runtime.h>
#include <stdint.h>

// DiffLogic: 3-layer differentiable logic network.
// Round 25: the last untested axis. R24's line-halving gave only 8% ->
// line/MSHR model refuted; with meta-path, occupancy, ILP, VALU all
// eliminated, the residual ~30us fused wall must be per-VMEM-INSTRUCTION
// cost (8 gather instrs/gate-eval, never varied in 18 rounds).
// Experiment: split-wave dual-gate gathers. u8 column = 256B = 32 lanes
// x 8B, so ONE instruction fetches gate g's column (lanes 0-31) AND gate
// g+1's (lanes 32-63): 8 instrs / 2 gates = half the VMEM count. Cost:
// 1 cndmask/gather col-select + 28 cndmask/pair coef-select (+20% VALU
// on a 20%-busy pipe). Lane computes 8 batch elems of its half's gate;
// named a0..a7 accumulators, unroll 1, (1024,4). Setup/prep = R24.

#define BATCH   256
#define IN_DIM  1024
#define WIDTH   64000
#define NGROUP  10
#define GSIZE   6400      // WIDTH / NGROUP
#define TAU     30.0f
#define NWAVE   16        // waves per block (1024 threads)
#define GPB3    256       // gates per block; 6400 % 256 == 0 -> no straddle
#define GPW3    (GPB3/NWAVE)   // 16 gates per wave (8 pairs)
#define NBLK3   (WIDTH/GPB3)   // 250 blocks -> 1 block/CU, single pass
#define BPG     (GSIZE/GPB3)   // 25 blocks per output group
#define MDW     36             // meta dwords per gate

#define TR_BLKS   64                   // transpose blocks
#define COEF_BLKS ((3*WIDTH)/256)      // 750
#define SETUP_BLKS (TR_BLKS + COEF_BLKS + 1)   // +1 zero-out block

typedef unsigned short ushort_t;

// h = c0 + c1*a + c2*b + c3*(a*b) = b*(c3*a+c2) + (c1*a+c0)  -- 3 FMA
static __device__ __forceinline__ float gate1(float4 c, float a, float b) {
    return fmaf(b, fmaf(c.w, a, c.z), fmaf(c.y, a, c.x));
}
// byte j of a uint2 as float (j compile-time) -> v_cvt_f32_ubyteN
static __device__ __forceinline__ float ub2(uint2 q, int j) {
    return (j < 4) ? (float)((q.x >> (8 * j)) & 0xFFu)
                   : (float)((q.y >> (8 * (j - 4))) & 0xFFu);
}

// ---------------------------------------------------------------- setup
// One dispatch, three independent jobs by blockIdx:
//   [0, 64)        transpose x:(256,1024) f32 -> xT8:(1024,256) u8 fixed
//   [64, 64+750)   softmax coefficients for all 3 layers
//   [814]          zero the 10KB output accumulator
__global__ __launch_bounds__(256) void setup_kernel(
    const float* __restrict__ x,
    const float* __restrict__ w1, const float* __restrict__ w2,
    const float* __restrict__ w3,
    uint8_t* __restrict__ xT8,
    float4* __restrict__ c1o, float4* __restrict__ c2o, float4* __restrict__ c3o,
    float* __restrict__ out_zero, int out_n)
{
    __shared__ float tile[64][65];
    const int bid = blockIdx.x;
    const int tid = threadIdx.x;

    if (bid < TR_BLKS) {
        const int c0 = (bid & 15) * 64;
        const int b0 = (bid >> 4) * 64;
        const int lt = tid & 63;
        const int wt = tid >> 6;
        for (int r = wt; r < 64; r += 4)
            tile[r][lt] = x[(b0 + r) * IN_DIM + c0 + lt];
        __syncthreads();
        for (int r = wt; r < 64; r += 4) {
            const float v = tile[lt][r];
            xT8[(c0 + r) * BATCH + b0 + lt] =
                (uint8_t)__float2int_rn(v * 255.0f);
        }
        return;
    }
    if (bid == TR_BLKS + COEF_BLKS) {
        for (int i = tid; i < out_n; i += 256) out_zero[i] = 0.f;
        return;
    }

    const int id = (bid - TR_BLKS) * 256 + tid;
    const int layer = id / WIDTH;
    const int j = id - layer * WIDTH;
    const float* w = (layer == 0) ? w1 : (layer == 1) ? w2 : w3;
    float4* cc     = (layer == 0) ? c1o : (layer == 1) ? c2o : c3o;

    const float4* w4 = (const float4*)(w + (size_t)j * 16);
    float4 q0 = w4[0], q1 = w4[1], q2 = w4[2], q3 = w4[3];
    float p[16] = {q0.x,q0.y,q0.z,q0.w, q1.x,q1.y,q1.z,q1.w,
                   q2.x,q2.y,q2.z,q2.w, q3.x,q3.y,q3.z,q3.w};
    float m = p[0];
    #pragma unroll
    for (int i = 1; i < 16; ++i) m = fmaxf(m, p[i]);
    float s = 0.f;
    #pragma unroll
    for (int i = 0; i < 16; ++i) { p[i] = __expf(p[i] - m); s += p[i]; }
    const float inv = 1.0f / s;
    float c0 = (p[8]+p[9]+p[10]+p[11]+p[12]+p[13]+p[14]+p[15]) * inv;
    float c1 = (p[2]+p[3]+p[6]+p[7] - p[8]-p[9]-p[12]-p[13]) * inv;
    float c2 = (p[4]+p[5]+p[6]+p[7] - p[8]-p[9]-p[10]-p[11]) * inv;
    float c3 = (p[1]-p[2]-p[4]-2.f*p[6]-p[7]+p[8]+2.f*p[9]+p[11]+p[13]-p[14]) * inv;
    cc[j] = make_float4(c0, c1, c2, c3);
}

// ---------------------------------------------------------------- tree prep
// One thread per final gate j: flatten its depth-3 tree into a single
// 36-dword record [iA(4)|iB(4)|K0..K6(28)]. Layer-1 coefs K0..K3 absorb the
// u8 fixed-point scale s=1/255: (c0, c1*s, c2*s, c3*s^2). K4..K6 unscaled.
__global__ __launch_bounds__(256) void prep_kernel(
    const int* __restrict__ ia1, const int* __restrict__ ib1,
    const int* __restrict__ ia2, const int* __restrict__ ib2,
    const int* __restrict__ ia3, const int* __restrict__ ib3,
    const float4* __restrict__ c1, const float4* __restrict__ c2,
    const float4* __restrict__ c3,
    int* __restrict__ meta)        // [WIDTH][36]
{
    const int j = blockIdx.x * 256 + threadIdx.x;
    if (j >= WIDTH) return;

    const int pa = ia3[j], pb = ib3[j];
    const int qaa = ia2[pa], qab = ib2[pa];
    const int qba = ia2[pb], qbb = ib2[pb];

    int* M = meta + (size_t)j * MDW;
    M[0] = ia1[qaa]; M[1] = ib1[qaa];
    M[2] = ia1[qab]; M[3] = ib1[qab];
    M[4] = ia1[qba]; M[5] = ib1[qba];
    M[6] = ia1[qbb]; M[7] = ib1[qbb];

    const float s1 = 1.0f / 255.0f;
    const float s2 = s1 * s1;
    float4* P = (float4*)(M + 8);
    float4 k;
    k = c1[qaa]; P[0] = make_float4(k.x, k.y * s1, k.z * s1, k.w * s2);
    k = c1[qab]; P[1] = make_float4(k.x, k.y * s1, k.z * s1, k.w * s2);
    k = c1[qba]; P[2] = make_float4(k.x, k.y * s1, k.z * s1, k.w * s2);
    k = c1[qbb]; P[3] = make_float4(k.x, k.y * s1, k.z * s1, k.w * s2);
    P[4] = c2[pa];  P[5] = c2[pb];
    P[6] = c3[j];
}

// ---------------------------------------------------------------- fused net
// Split-wave dual-gate: lanes 0-31 evaluate gate g, lanes 32-63 gate g+1.
// One uint2 gather per column fetches BOTH gates' columns (8B/lane x 32
// lanes = full 256B u8 column per half-wave). Lane owns 8 batch elems.
#define TREE_ELEM(j) do {                                                      \
    const float v0 = ub2(q0, j), v1 = ub2(q1, j);                              \
    const float v2 = ub2(q2, j), v3 = ub2(q3, j);                              \
    const float v4 = ub2(q4, j), v5 = ub2(q5, j);                              \
    const float v6 = ub2(q6, j), v7 = ub2(q7, j);                              \
    const float haa = gate1(K0, v0, v1);                                       \
    const float hab = gate1(K1, v2, v3);                                       \
    const float hba = gate1(K2, v4, v5);                                       \
    const float hbb = gate1(K3, v6, v7);                                       \
    const float h2a = gate1(K4, haa, hab);                                     \
    const float h2b = gate1(K5, hba, hbb);                                     \
    a##j += gate1(K6, h2a, h2b);                                               \
} while (0)

__global__ __launch_bounds__(1024, 4) void fused_kernel(
    const uint8_t* __restrict__ xT8,
    const int*     __restrict__ meta,
    float*         __restrict__ red_out)
{
    __shared__ float4 sredA[NWAVE][64];      // 16 KB (elems 0-3)
    __shared__ float4 sredB[NWAVE][64];      // 16 KB (elems 4-7)

    const int tid  = threadIdx.x;
    const int lane = tid & 63;
    const int wu   = __builtin_amdgcn_readfirstlane(tid >> 6);
    const int g0   = blockIdx.x * GPB3 + wu * GPW3;   // uniform

    const bool lo  = (lane < 32);            // which gate of the pair
    const int sub8 = (lane & 31) * 8;        // byte offset within column

    float a0 = 0.f, a1 = 0.f, a2 = 0.f, a3 = 0.f;
    float a4 = 0.f, a5 = 0.f, a6 = 0.f, a7 = 0.f;

    #pragma unroll 1
    for (int i = 0; i < GPW3 / 2; ++i) {     // 8 pairs
        const int g = g0 + 2 * i;            // uniform
        const int* mpg = meta + (size_t)g * MDW;      // -> s_load
        const int* mph = mpg + MDW;
        const int4 giA = *(const int4*)(mpg);
        const int4 giB = *(const int4*)(mpg + 4);
        const int4 hiA = *(const int4*)(mph);
        const int4 hiB = *(const int4*)(mph + 4);

        // 8 dual-gate gathers: col chosen per half-wave, 8B/lane
        const uint2 q0 = *(const uint2*)(xT8 + (size_t)(lo ? giA.x : hiA.x) * BATCH + sub8);
        const uint2 q1 = *(const uint2*)(xT8 + (size_t)(lo ? giA.y : hiA.y) * BATCH + sub8);
        const uint2 q2 = *(const uint2*)(xT8 + (size_t)(lo ? giA.z : hiA.z) * BATCH + sub8);
        const uint2 q3 = *(const uint2*)(xT8 + (size_t)(lo ? giA.w : hiA.w) * BATCH + sub8);
        const uint2 q4 = *(const uint2*)(xT8 + (size_t)(lo ? giB.x : hiB.x) * BATCH + sub8);
        const uint2 q5 = *(const uint2*)(xT8 + (size_t)(lo ? giB.y : hiB.y) * BATCH + sub8);
        const uint2 q6 = *(const uint2*)(xT8 + (size_t)(lo ? giB.z : hiB.z) * BATCH + sub8);
        const uint2 q7 = *(const uint2*)(xT8 + (size_t)(lo ? giB.w : hiB.w) * BATCH + sub8);

        // coefs for both gates (s_load), selected per half-wave (cndmask)
        const float4 gK0 = *(const float4*)(mpg + 8);
        const float4 gK1 = *(const float4*)(mpg + 12);
        const float4 gK2 = *(const float4*)(mpg + 16);
        const float4 gK3 = *(const float4*)(mpg + 20);
        const float4 gK4 = *(const float4*)(mpg + 24);
        const float4 gK5 = *(const float4*)(mpg + 28);
        const float4 gK6 = *(const float4*)(mpg + 32);
        const float4 hK0 = *(const float4*)(mph + 8);
        const float4 hK1 = *(const float4*)(mph + 12);
        const float4 hK2 = *(const float4*)(mph + 16);
        const float4 hK3 = *(const float4*)(mph + 20);
        const float4 hK4 = *(const float4*)(mph + 24);
        const float4 hK5 = *(const float4*)(mph + 28);
        const float4 hK6 = *(const float4*)(mph + 32);

        const float4 K0 = lo ? gK0 : hK0;
        const float4 K1 = lo ? gK1 : hK1;
        const float4 K2 = lo ? gK2 : hK2;
        const float4 K3 = lo ? gK3 : hK3;
        const float4 K4 = lo ? gK4 : hK4;
        const float4 K5 = lo ? gK5 : hK5;
        const float4 K6 = lo ? gK6 : hK6;

        TREE_ELEM(0); TREE_ELEM(1); TREE_ELEM(2); TREE_ELEM(3);
        TREE_ELEM(4); TREE_ELEM(5); TREE_ELEM(6); TREE_ELEM(7);
    }

    // ---- block reduction + grouped atomic add (block fully inside a group)
    sredA[wu][lane] = make_float4(a0, a1, a2, a3);
    sredB[wu][lane] = make_float4(a4, a5, a6, a7);
    __syncthreads();
    if (wu == 0) {
        float4 tA = sredA[0][lane];
        float4 tB = sredB[0][lane];
        #pragma unroll
        for (int w = 1; w < NWAVE; ++w) {
            const float4 pA = sredA[w][lane];
            const float4 pB = sredB[w][lane];
            tA.x += pA.x; tA.y += pA.y; tA.z += pA.z; tA.w += pA.w;
            tB.x += pB.x; tB.y += pB.y; tB.z += pB.z; tB.w += pB.w;
        }
        const float sc = 1.0f / TAU;
        const int grp = blockIdx.x / BPG;
        const int b0 = (lane & 31) * 8;      // lanes l and l+32 share b0: atomics commute
        atomicAdd(&red_out[(b0 + 0) * NGROUP + grp], tA.x * sc);
        atomicAdd(&red_out[(b0 + 1) * NGROUP + grp], tA.y * sc);
        atomicAdd(&red_out[(b0 + 2) * NGROUP + grp], tA.z * sc);
        atomicAdd(&red_out[(b0 + 3) * NGROUP + grp], tA.w * sc);
        atomicAdd(&red_out[(b0 + 4) * NGROUP + grp], tB.x * sc);
        atomicAdd(&red_out[(b0 + 5) * NGROUP + grp], tB.y * sc);
        atomicAdd(&red_out[(b0 + 6) * NGROUP + grp], tB.z * sc);
        atomicAdd(&red_out[(b0 + 7) * NGROUP + grp], tB.w * sc);
    }
}

// ---------------------------------------------------------------- launch
extern "C" void kernel_launch(void* const* d_in, const int* in_sizes, int n_in,
                              void* d_out, int out_size, void* d_ws, size_t ws_size,
                              hipStream_t stream)
{
    const float* x   = (const float*)d_in[0];
    const float* w1  = (const float*)d_in[1];
    const float* w2  = (const float*)d_in[2];
    const float* w3  = (const float*)d_in[3];
    const int*   ia1 = (const int*)d_in[4];
    const int*   ib1 = (const int*)d_in[5];
    const int*   ia2 = (const int*)d_in[6];
    const int*   ib2 = (const int*)d_in[7];
    const int*   ia3 = (const int*)d_in[8];
    const int*   ib3 = (const int*)d_in[9];
    float* out = (float*)d_out;

    // workspace: xT8 (0.25MB) | meta (9.2MB) | c1,c2,c3 (3MB) ~= 12.5MB
    char* ws = (char*)d_ws;
    uint8_t* xT8 = (uint8_t*)ws;
    int*    meta = (int*)(ws + (size_t)IN_DIM * BATCH);
    float4*   c1 = (float4*)(meta + (size_t)WIDTH * MDW);
    float4*   c2 = c1 + WIDTH;
    float4*   c3 = c2 + WIDTH;

    setup_kernel<<<SETUP_BLKS, 256, 0, stream>>>(x, w1, w2, w3, xT8,
                                                 c1, c2, c3, out, out_size);
    prep_kernel<<<WIDTH / 256, 256, 0, stream>>>(ia1, ib1, ia2, ib2, ia3, ib3,
                                                 c1, c2, c3, meta);
    fused_kernel<<<NBLK3, 1024, 0, stream>>>(xT8, meta, out);
}